// Round 2
// baseline (882.761 us; speedup 1.0000x reference)
//
#include <hip/hip_runtime.h>
#include <hip/hip_bf16.h>

// Problem constants
#define NF 32          // n_features
#define NCH 64         // n_channels
#define TRAW 16384     // raw samples
#define TPAD 16448     // TRAW + 64 (left reflect pad)
#define TP 4112        // TPAD / 4
#define TE 4104        // TP - 8  (after encoder MA, kernel size 9)
#define TD 4096        // TE - 8  (after decoder MA) == TRAW/4

// Workspace layout (floats)
#define OFF_SPAD   0u                     // [32][16448]
#define OFF_AMEAN  526336u                // [32][4112]
#define OFF_ACOV   657920u                // [4112][1024] t-major
#define OFF_XMEAN  4868608u               // [32][4104]
#define OFF_XCOV   4999936u               // [4104][1024] t-major
// reuse: AMEANT aliases AMEAN (consumed), ACOVT aliases ACOV (consumed)
#define OFF_AMEANT OFF_AMEAN              // [32][4096]
#define OFF_ACOVT  OFF_ACOV               // [4096][1024]

// ---------------------------------------------------------------------------
// 1) s_pad[f,t] = sum_c W_enc[f,c] * y_pad[c,t],  y_pad[c,t] = y[c, |t-64|]
__global__ void senc_kernel(const float* __restrict__ y,
                            const float* __restrict__ Wenc,
                            float* __restrict__ spad) {
    int t = blockIdx.x * 256 + threadIdx.x;
    int f = blockIdx.y;
    if (t >= TPAD) return;
    int tt = (t >= 64) ? (t - 64) : (64 - t);   // reflect pad
    float acc = 0.f;
#pragma unroll
    for (int c = 0; c < NCH; ++c)
        acc = fmaf(Wenc[f * NCH + c], y[c * TRAW + tt], acc);
    spad[f * TPAD + t] = acc;
}

// ---------------------------------------------------------------------------
// 2) per-t4 stats: a_mean[f,t4], a_cov[t4][c][s]  (8 t4 per block)
__global__ __launch_bounds__(256) void stats_kernel(const float* __restrict__ spad,
                                                    float* __restrict__ amean,
                                                    float* __restrict__ acov) {
    __shared__ float sab[32][33];   // padded (bank conflicts)
    __shared__ float mu[32][9];
    int tid = threadIdx.x;
    int t0 = blockIdx.x * 8;        // 514 blocks * 8 = 4112
#pragma unroll
    for (int i = 0; i < 4; ++i) {
        int idx = tid + 256 * i;    // 0..1023
        int f = idx >> 5, j = idx & 31;
        sab[f][j] = fabsf(spad[f * TPAD + t0 * 4 + j]);
    }
    __syncthreads();
    {
        int f = tid >> 3, tt = tid & 7;
        float m = 0.25f * (sab[f][tt * 4] + sab[f][tt * 4 + 1] +
                           sab[f][tt * 4 + 2] + sab[f][tt * 4 + 3]);
        mu[f][tt] = m;
        amean[f * TP + t0 + tt] = m;
    }
    __syncthreads();
    const float inv3 = 1.f / 3.f;
#pragma unroll
    for (int e = 0; e < 32; ++e) {
        int flat = e * 256 + tid;   // 0..8191
        int tt = flat >> 10, r = flat & 1023;
        int c = r >> 5, s = r & 31;
        float mc = mu[c][tt], ms = mu[s][tt];
        float acc = 0.f;
#pragma unroll
        for (int d = 0; d < 4; ++d)
            acc += (sab[c][tt * 4 + d] - mc) * (sab[s][tt * 4 + d] - ms);
        acov[(size_t)(t0 + tt) * 1024 + r] = acc * inv3;
    }
}

// ---------------------------------------------------------------------------
// 3/5) mean MA: out[c,t] = b[c] + in[c,t+8] + sum_{k<8,C} w[c,C,k]*in[C,t+k]
__global__ void mamean_kernel(const float* __restrict__ in, int instride,
                              const float* __restrict__ w,
                              const float* __restrict__ b,
                              float* __restrict__ outp, int Tout) {
    int t = blockIdx.x * 256 + threadIdx.x;
    int c = blockIdx.y;
    if (t >= Tout) return;
    float acc = b[c] + in[c * instride + t + 8];
    for (int C = 0; C < NF; ++C) {
#pragma unroll
        for (int k = 0; k < 8; ++k)
            acc = fmaf(w[(c * NF + C) * 8 + k], in[C * instride + t + k], acc);
    }
    outp[c * Tout + t] = acc;
}

// ---------------------------------------------------------------------------
// 4/6) cov MA: Aout[t] = scale * sum_{k=0..8} F_k * Ain[t+k] * F_k^T
//      F_k = maw[:,:,k] for k<8, identity for k=8.
//      One wave per t (4 t per block). fe staged in LDS as fe[k][C][c].
__global__ __launch_bounds__(256) void macov_kernel(const float* __restrict__ Ain,
                                                    const float* __restrict__ maw,
                                                    const float* __restrict__ scale_ptr,
                                                    float* __restrict__ Aout,
                                                    int Tout) {
    __shared__ float fe[9 * 1024];   // fe[k*1024 + C*32 + c] = filtr[c][C][k]
    __shared__ float Bl[4][1024];    // per-wave B = F_k * A
    int tid = threadIdx.x;
#pragma unroll
    for (int i = 0; i < 36; ++i) {
        int idx = tid + 256 * i;     // 0..9215
        int k = idx >> 10, r = idx & 1023;
        int C = r >> 5, c = r & 31;
        fe[idx] = (k < 8) ? maw[(c * NF + C) * 8 + k] : (c == C ? 1.f : 0.f);
    }
    __syncthreads();
    int w = tid >> 6;                // wave id
    int l = tid & 63;
    int t = blockIdx.x * 4 + w;      // Tout divisible by 4 (4104, 4096)
    int hi = l >> 5, s = l & 31;     // lane owns (c = hi*16+e, s)
    float acc[16];
#pragma unroll
    for (int e = 0; e < 16; ++e) acc[e] = 0.f;
    float* Bw = Bl[w];
    for (int k = 0; k < 8; ++k) {
        const float* Arow = Ain + (size_t)(t + k) * 1024;
        const float* fek = fe + k * 1024;
        // step 1: B[c][S] = sum_C fe[k][C][c] * A[C][S], S = s
        float bacc[16];
#pragma unroll
        for (int e = 0; e < 16; ++e) bacc[e] = 0.f;
#pragma unroll 4
        for (int C = 0; C < 32; ++C) {
            float a = Arow[C * 32 + s];
            const float* fr = fek + C * 32 + hi * 16;
#pragma unroll
            for (int e = 0; e < 16; ++e) bacc[e] = fmaf(fr[e], a, bacc[e]);
        }
#pragma unroll
        for (int e = 0; e < 16; ++e) Bw[(hi * 16 + e) * 32 + s] = bacc[e];
        __syncthreads();
        // step 2: acc[c][s] += sum_S B[c][S] * fe[k][S][s]
        float fs[32];
#pragma unroll
        for (int S = 0; S < 32; ++S) fs[S] = fek[S * 32 + s];
#pragma unroll
        for (int e = 0; e < 16; ++e) {
            const float* Br = Bw + (hi * 16 + e) * 32;
            float a2 = 0.f;
#pragma unroll
            for (int S = 0; S < 32; ++S) a2 = fmaf(Br[S], fs[S], a2);
            acc[e] += a2;
        }
        __syncthreads();
    }
    // k = 8: identity term
    {
        const float* Arow = Ain + (size_t)(t + 8) * 1024;
#pragma unroll
        for (int e = 0; e < 16; ++e) acc[e] += Arow[(hi * 16 + e) * 32 + s];
    }
    float sc = scale_ptr ? *scale_ptr : 1.f;
    float* Orow = Aout + (size_t)t * 1024;
#pragma unroll
    for (int e = 0; e < 16; ++e) Orow[(hi * 16 + e) * 32 + s] = acc[e] * sc;
}

// ---------------------------------------------------------------------------
// 7) y_mean rows 0..63: out[o,t] = sum_f Wdec[o,f]*a_mean_t[f,t/4]*sgn(spad[f,t+64])
__global__ void ymean_kernel(const float* __restrict__ spad,
                             const float* __restrict__ ameant,
                             const float* __restrict__ Wdec,
                             float* __restrict__ out) {
    int t = blockIdx.x * 256 + threadIdx.x;   // < 16384
    int o = blockIdx.y;
    int t4 = t >> 2;
    float acc = 0.f;
#pragma unroll
    for (int f = 0; f < NF; ++f) {
        float sp = spad[f * TPAD + 64 + t];
        float sgn = (sp > 0.f) ? 1.f : (sp < 0.f ? -1.f : 0.f);
        acc = fmaf(Wdec[o * NF + f], ameant[f * TD + t4] * sgn, acc);
    }
    out[o * TRAW + t] = acc;
}

// ---------------------------------------------------------------------------
// 8) y_cov rows 64..4159: per t4, M = Wdec * A * Wdec^T, write 4x along t
__global__ __launch_bounds__(256) void ycov_kernel(const float* __restrict__ Acovt,
                                                   const float* __restrict__ Wdec,
                                                   float* __restrict__ out) {
    __shared__ float A[1024];
    __shared__ float Wt[32 * 64];   // Wt[i*64+o] = Wdec[o*32+i]
    __shared__ float Bm[64 * 32];   // B[o*32+I]
    int tid = threadIdx.x;
    int t4 = blockIdx.x;
#pragma unroll
    for (int i = 0; i < 4; ++i) A[tid + 256 * i] = Acovt[(size_t)t4 * 1024 + tid + 256 * i];
#pragma unroll
    for (int i = 0; i < 8; ++i) {
        int idx = tid + 256 * i;    // 0..2047
        int o = idx & 63, ii = idx >> 6;
        Wt[idx] = Wdec[o * NF + ii];   // Wt[ii*64+o], consecutive write
    }
    __syncthreads();
    // B[o][I] = sum_i Wdec[o,i] * A[i*32+I]
#pragma unroll
    for (int e = 0; e < 8; ++e) {
        int flat = e * 256 + tid;   // 0..2047
        int o = flat >> 5, I = flat & 31;
        float acc = 0.f;
#pragma unroll
        for (int i = 0; i < 32; ++i) acc = fmaf(Wt[i * 64 + o], A[i * 32 + I], acc);
        Bm[flat] = acc;
    }
    __syncthreads();
    // M[o][O] = sum_I B[o*32+I] * Wt[I*64+O]; write float4 (t-repeat of 4)
#pragma unroll
    for (int e = 0; e < 16; ++e) {
        int flat = e * 256 + tid;   // 0..4095 = o*64 + O
        int o = flat >> 6, O = flat & 63;
        float acc = 0.f;
#pragma unroll
        for (int I = 0; I < 32; ++I) acc = fmaf(Bm[o * 32 + I], Wt[I * 64 + O], acc);
        float4* dst = (float4*)out + ((size_t)(64 + flat) * (TRAW / 4) + t4);
        *dst = make_float4(acc, acc, acc, acc);
    }
}

// ---------------------------------------------------------------------------
extern "C" void kernel_launch(void* const* d_in, const int* in_sizes, int n_in,
                              void* d_out, int out_size, void* d_ws, size_t ws_size,
                              hipStream_t stream) {
    const float* y      = (const float*)d_in[0];
    const float* Wenc   = (const float*)d_in[1];
    const float* Wdec   = (const float*)d_in[2];
    const float* mawE   = (const float*)d_in[3];
    const float* mabE   = (const float*)d_in[4];
    const float* mawD   = (const float*)d_in[5];
    const float* mabD   = (const float*)d_in[6];
    const float* covsc  = (const float*)d_in[7];
    float* out = (float*)d_out;
    float* ws  = (float*)d_ws;

    float* spad   = ws + OFF_SPAD;
    float* amean  = ws + OFF_AMEAN;
    float* acov   = ws + OFF_ACOV;
    float* xmean  = ws + OFF_XMEAN;
    float* xcov   = ws + OFF_XCOV;
    float* ameant = ws + OFF_AMEANT;
    float* acovt  = ws + OFF_ACOVT;

    // 1) spatial encode + pad
    senc_kernel<<<dim3((TPAD + 255) / 256, NF), 256, 0, stream>>>(y, Wenc, spad);
    // 2) downsample stats
    stats_kernel<<<dim3(TP / 8), 256, 0, stream>>>(spad, amean, acov);
    // 3) encoder mean MA
    mamean_kernel<<<dim3((TE + 255) / 256, NF), 256, 0, stream>>>(amean, TP, mawE, mabE, xmean, TE);
    // 4) encoder cov MA (scaled by cov_scaler)
    macov_kernel<<<dim3(TE / 4), 256, 0, stream>>>(acov, mawE, covsc, xcov, TE);
    // 5) decoder mean MA
    mamean_kernel<<<dim3((TD + 255) / 256, NF), 256, 0, stream>>>(xmean, TE, mawD, mabD, ameant, TD);
    // 6) decoder cov MA
    macov_kernel<<<dim3(TD / 4), 256, 0, stream>>>(xcov, mawD, nullptr, acovt, TD);
    // 7) y_mean
    ymean_kernel<<<dim3(TRAW / 256, NCH), 256, 0, stream>>>(spad, ameant, Wdec, out);
    // 8) y_cov
    ycov_kernel<<<dim3(TD), 256, 0, stream>>>(acovt, Wdec, out);
}

// Round 4
// 683.130 us; speedup vs baseline: 1.2922x; 1.2922x over previous
//
#include <hip/hip_runtime.h>
#include <hip/hip_bf16.h>

// Problem constants
#define NF 32          // n_features
#define NCH 64         // n_channels
#define TRAW 16384     // raw samples
#define TPAD 16448     // TRAW + 64 (left reflect pad)
#define TP 4112        // TPAD / 4
#define TE 4104        // TP - 8  (after encoder MA, kernel size 9)
#define TD 4096        // TE - 8  (after decoder MA) == TRAW/4

// Workspace layout (floats)
#define OFF_SPAD   0u                     // [32][16448]
#define OFF_AMEAN  526336u                // [32][4112]
#define OFF_ACOV   657920u                // [4112][1024] t-major
#define OFF_XMEAN  4868608u               // [32][4104]
#define OFF_XCOV   4999936u               // [4104][1024] t-major
// reuse: AMEANT aliases AMEAN (consumed), ACOVT aliases ACOV (consumed)
#define OFF_AMEANT OFF_AMEAN              // [32][4096]
#define OFF_ACOVT  OFF_ACOV               // [4096][1024]

// ---------------------------------------------------------------------------
// 1) s_pad[f,t] = sum_c W_enc[f,c] * y_pad[c,t],  y_pad[c,t] = y[c, |t-64|]
__global__ void senc_kernel(const float* __restrict__ y,
                            const float* __restrict__ Wenc,
                            float* __restrict__ spad) {
    int t = blockIdx.x * 256 + threadIdx.x;
    int f = blockIdx.y;
    if (t >= TPAD) return;
    int tt = (t >= 64) ? (t - 64) : (64 - t);   // reflect pad
    float acc = 0.f;
#pragma unroll
    for (int c = 0; c < NCH; ++c)
        acc = fmaf(Wenc[f * NCH + c], y[c * TRAW + tt], acc);
    spad[f * TPAD + t] = acc;
}

// ---------------------------------------------------------------------------
// 2) per-t4 stats: a_mean[f,t4], a_cov[t4][c][s]  (8 t4 per block)
__global__ __launch_bounds__(256) void stats_kernel(const float* __restrict__ spad,
                                                    float* __restrict__ amean,
                                                    float* __restrict__ acov) {
    __shared__ float sab[32][33];   // padded (bank conflicts)
    __shared__ float mu[32][9];
    int tid = threadIdx.x;
    int t0 = blockIdx.x * 8;        // 514 blocks * 8 = 4112
#pragma unroll
    for (int i = 0; i < 4; ++i) {
        int idx = tid + 256 * i;    // 0..1023
        int f = idx >> 5, j = idx & 31;
        sab[f][j] = fabsf(spad[f * TPAD + t0 * 4 + j]);
    }
    __syncthreads();
    {
        int f = tid >> 3, tt = tid & 7;
        float m = 0.25f * (sab[f][tt * 4] + sab[f][tt * 4 + 1] +
                           sab[f][tt * 4 + 2] + sab[f][tt * 4 + 3]);
        mu[f][tt] = m;
        amean[f * TP + t0 + tt] = m;
    }
    __syncthreads();
    const float inv3 = 1.f / 3.f;
#pragma unroll
    for (int e = 0; e < 32; ++e) {
        int flat = e * 256 + tid;   // 0..8191
        int tt = flat >> 10, r = flat & 1023;
        int c = r >> 5, s = r & 31;
        float mc = mu[c][tt], ms = mu[s][tt];
        float acc = 0.f;
#pragma unroll
        for (int d = 0; d < 4; ++d)
            acc += (sab[c][tt * 4 + d] - mc) * (sab[s][tt * 4 + d] - ms);
        acov[(size_t)(t0 + tt) * 1024 + r] = acc * inv3;
    }
}

// ---------------------------------------------------------------------------
// 3/5) mean MA: out[c,t] = b[c] + in[c,t+8] + sum_{k<8,C} w[c,C,k]*in[C,t+k]
__global__ void mamean_kernel(const float* __restrict__ in, int instride,
                              const float* __restrict__ w,
                              const float* __restrict__ b,
                              float* __restrict__ outp, int Tout) {
    int t = blockIdx.x * 256 + threadIdx.x;
    int c = blockIdx.y;
    if (t >= Tout) return;
    float acc = b[c] + in[c * instride + t + 8];
    for (int C = 0; C < NF; ++C) {
#pragma unroll
        for (int k = 0; k < 8; ++k)
            acc = fmaf(w[(c * NF + C) * 8 + k], in[C * instride + t + k], acc);
    }
    outp[c * Tout + t] = acc;
}

// ---------------------------------------------------------------------------
// 4/6) cov MA: Aout[t] = scale * sum_{k=0..8} F_k * Ain[t+k] * F_k^T
//      F_k = maw[:,:,k] for k<8, identity for k=8.
//      One wave per t (4 t per block). fe staged in LDS as fe[k][C][c].
__global__ __launch_bounds__(256) void macov_kernel(const float* __restrict__ Ain,
                                                    const float* __restrict__ maw,
                                                    const float* __restrict__ scale_ptr,
                                                    float* __restrict__ Aout,
                                                    int Tout) {
    __shared__ float fe[9 * 1024];   // fe[k*1024 + C*32 + c] = filtr[c][C][k]
    __shared__ float Bl[4][1024];    // per-wave B = F_k * A
    int tid = threadIdx.x;
#pragma unroll
    for (int i = 0; i < 36; ++i) {
        int idx = tid + 256 * i;     // 0..9215
        int k = idx >> 10, r = idx & 1023;
        int C = r >> 5, c = r & 31;
        fe[idx] = (k < 8) ? maw[(c * NF + C) * 8 + k] : (c == C ? 1.f : 0.f);
    }
    __syncthreads();
    int w = tid >> 6;                // wave id
    int l = tid & 63;
    int t = blockIdx.x * 4 + w;      // Tout divisible by 4 (4104, 4096)
    int hi = l >> 5, s = l & 31;     // lane owns (c = hi*16+e, s)
    float acc[16];
#pragma unroll
    for (int e = 0; e < 16; ++e) acc[e] = 0.f;
    float* Bw = Bl[w];
    for (int k = 0; k < 8; ++k) {
        const float* Arow = Ain + (size_t)(t + k) * 1024;
        const float* fek = fe + k * 1024;
        // step 1: B[c][S] = sum_C fe[k][C][c] * A[C][S], S = s
        float bacc[16];
#pragma unroll
        for (int e = 0; e < 16; ++e) bacc[e] = 0.f;
#pragma unroll 4
        for (int C = 0; C < 32; ++C) {
            float a = Arow[C * 32 + s];
            const float* fr = fek + C * 32 + hi * 16;
#pragma unroll
            for (int e = 0; e < 16; ++e) bacc[e] = fmaf(fr[e], a, bacc[e]);
        }
#pragma unroll
        for (int e = 0; e < 16; ++e) Bw[(hi * 16 + e) * 32 + s] = bacc[e];
        __syncthreads();
        // step 2: acc[c][s] += sum_S B[c][S] * fe[k][S][s]
        float fs[32];
#pragma unroll
        for (int S = 0; S < 32; ++S) fs[S] = fek[S * 32 + s];
#pragma unroll
        for (int e = 0; e < 16; ++e) {
            const float* Br = Bw + (hi * 16 + e) * 32;
            float a2 = 0.f;
#pragma unroll
            for (int S = 0; S < 32; ++S) a2 = fmaf(Br[S], fs[S], a2);
            acc[e] += a2;
        }
        __syncthreads();
    }
    // k = 8: identity term
    {
        const float* Arow = Ain + (size_t)(t + 8) * 1024;
#pragma unroll
        for (int e = 0; e < 16; ++e) acc[e] += Arow[(hi * 16 + e) * 32 + s];
    }
    float sc = scale_ptr ? *scale_ptr : 1.f;
    float* Orow = Aout + (size_t)t * 1024;
#pragma unroll
    for (int e = 0; e < 16; ++e) Orow[(hi * 16 + e) * 32 + s] = acc[e] * sc;
}

// ---------------------------------------------------------------------------
// 7) y_mean rows 0..63: out[o,t] = sum_f Wdec[o,f]*a_mean_t[f,t/4]*sgn(spad[f,t+64])
__global__ void ymean_kernel(const float* __restrict__ spad,
                             const float* __restrict__ ameant,
                             const float* __restrict__ Wdec,
                             float* __restrict__ out) {
    int t = blockIdx.x * 256 + threadIdx.x;   // < 16384
    int o = blockIdx.y;
    int t4 = t >> 2;
    float acc = 0.f;
#pragma unroll
    for (int f = 0; f < NF; ++f) {
        float sp = spad[f * TPAD + 64 + t];
        float sgn = (sp > 0.f) ? 1.f : (sp < 0.f ? -1.f : 0.f);
        acc = fmaf(Wdec[o * NF + f], ameant[f * TD + t4] * sgn, acc);
    }
    out[o * TRAW + t] = acc;
}

// ---------------------------------------------------------------------------
// 8) y_cov rows 64..4159. Block owns 4 consecutive t4 (= 16 t = 64B per row).
//    Per t4: M = Wdec * A * Wdec^T.  Writes are 64B-full-line coalesced:
//    4 consecutive lanes write 4 consecutive float4 within one row.
//    GRID MUST BE TD/4 = 1024 BLOCKS (4 t4 per block).
#define A4S 1032   // padded stride (floats) for A4 tiles
#define B4S 2056   // padded stride (floats) for B tiles
__global__ __launch_bounds__(256) void ycov_kernel(const float* __restrict__ Acovt,
                                                   const float* __restrict__ Wdec,
                                                   float* __restrict__ out) {
    __shared__ float A4[4 * A4S];   // A4[t4l*A4S + i*32 + I]
    __shared__ float Wt[32 * 64];   // Wt[i*64 + o] = Wdec[o*32 + i]
    __shared__ float B4[4 * B4S];   // B4[t4l*B4S + o*32 + I]
    int tid = threadIdx.x;
    int T0 = blockIdx.x * 4;        // t4 base; gridDim.x == 1024

    // stage A rows T0..T0+3 (coalesced float4 loads)
    {
        const float4* src = (const float4*)(Acovt + (size_t)T0 * 1024);
        float4* dst = (float4*)A4;  // A4S/4 = 258 float4 stride per tile
#pragma unroll
        for (int i = 0; i < 4; ++i) {
            int idx = tid + 256 * i;          // 0..1023 float4s
            int t4l = idx >> 8, j = idx & 255;
            dst[t4l * (A4S / 4) + j] = src[idx];
        }
    }
    // stage Wt (coalesced global read)
#pragma unroll
    for (int i = 0; i < 8; ++i) {
        int idx = tid + 256 * i;              // 0..2047
        int o = idx >> 5, ii = idx & 31;
        Wt[ii * 64 + o] = Wdec[idx];
    }
    __syncthreads();

    // B-stage: B[t4][o][I] = sum_i Wdec[o][i] * A[t4][i][I]
    {
        int t4l = tid >> 6, I = tid & 31, half = (tid >> 5) & 1;
        float areg[32];
        const float* Ab = A4 + t4l * A4S + I;
#pragma unroll
        for (int i = 0; i < 32; ++i) areg[i] = Ab[i * 32];
        float* Bb = B4 + t4l * B4S + I;
#pragma unroll 4
        for (int oj = 0; oj < 32; ++oj) {
            int o = half * 32 + oj;
            float acc = 0.f;
#pragma unroll
            for (int i = 0; i < 32; ++i) acc = fmaf(Wt[i * 64 + o], areg[i], acc);
            Bb[o * 32] = acc;
        }
    }
    __syncthreads();

    // M-stage: thread owns (O = tid>>2, t4l = tid&3), loops o = 0..63.
    // Each value is one float4 store (4-fold t-repeat); 4 consecutive lanes
    // write 4 consecutive float4 within one output row = full 64B line.
    {
        int O = tid >> 2, t4l = tid & 3;
        float wreg[32];
#pragma unroll
        for (int I = 0; I < 32; ++I) wreg[I] = Wt[I * 64 + O];
        float4* out4 = (float4*)out;
        const float* Bbase = B4 + t4l * B4S;
#pragma unroll 2
        for (int o = 0; o < 64; ++o) {
            const float* Br = Bbase + o * 32;
            float acc = 0.f;
#pragma unroll
            for (int I = 0; I < 32; ++I) acc = fmaf(Br[I], wreg[I], acc);
            size_t r = 64 + o * 64 + O;       // output row
            out4[r * (TRAW / 4) + T0 + t4l] = make_float4(acc, acc, acc, acc);
        }
    }
}

// ---------------------------------------------------------------------------
extern "C" void kernel_launch(void* const* d_in, const int* in_sizes, int n_in,
                              void* d_out, int out_size, void* d_ws, size_t ws_size,
                              hipStream_t stream) {
    const float* y      = (const float*)d_in[0];
    const float* Wenc   = (const float*)d_in[1];
    const float* Wdec   = (const float*)d_in[2];
    const float* mawE   = (const float*)d_in[3];
    const float* mabE   = (const float*)d_in[4];
    const float* mawD   = (const float*)d_in[5];
    const float* mabD   = (const float*)d_in[6];
    const float* covsc  = (const float*)d_in[7];
    float* out = (float*)d_out;
    float* ws  = (float*)d_ws;

    float* spad   = ws + OFF_SPAD;
    float* amean  = ws + OFF_AMEAN;
    float* acov   = ws + OFF_ACOV;
    float* xmean  = ws + OFF_XMEAN;
    float* xcov   = ws + OFF_XCOV;
    float* ameant = ws + OFF_AMEANT;
    float* acovt  = ws + OFF_ACOVT;

    // 1) spatial encode + pad
    senc_kernel<<<dim3((TPAD + 255) / 256, NF), 256, 0, stream>>>(y, Wenc, spad);
    // 2) downsample stats
    stats_kernel<<<dim3(TP / 8), 256, 0, stream>>>(spad, amean, acov);
    // 3) encoder mean MA
    mamean_kernel<<<dim3((TE + 255) / 256, NF), 256, 0, stream>>>(amean, TP, mawE, mabE, xmean, TE);
    // 4) encoder cov MA (scaled by cov_scaler)
    macov_kernel<<<dim3(TE / 4), 256, 0, stream>>>(acov, mawE, covsc, xcov, TE);
    // 5) decoder mean MA
    mamean_kernel<<<dim3((TD + 255) / 256, NF), 256, 0, stream>>>(xmean, TE, mawD, mabD, ameant, TD);
    // 6) decoder cov MA
    macov_kernel<<<dim3(TD / 4), 256, 0, stream>>>(xcov, mawD, nullptr, acovt, TD);
    // 7) y_mean
    ymean_kernel<<<dim3(TRAW / 256, NCH), 256, 0, stream>>>(spad, ameant, Wdec, out);
    // 8) y_cov  — 4 t4 per block
    ycov_kernel<<<dim3(TD / 4), 256, 0, stream>>>(acovt, Wdec, out);
}